// Round 1
// baseline (172.557 us; speedup 1.0000x reference)
//
#include <hip/hip_runtime.h>
#include <math.h>

#define BDIM 256

// Anchors per layer: l0 = mask[6,7,8], l1 = [3,4,5], l2 = [0,1,2]
__device__ __constant__ float c_aw[3][3] = {{116.f,156.f,373.f},{30.f,62.f,59.f},{10.f,16.f,33.f}};
__device__ __constant__ float c_ah[3][3] = {{90.f,198.f,326.f},{61.f,45.f,119.f},{13.f,30.f,23.f}};

// Block-range mapping: layer0 -> 16 blocks (4056 cells), layer1 -> 64 (16224),
// layer2 -> 254 (64896). Total 334 blocks. No block straddles layers.
// acc layout (doubles, per layer 7): 0 bce_xy_sum, 1 wh_sum, 2 conf_bce_sum,
//   3 cls_bce_sum, 4 obj_sum, 5 s1_sum(=obj*bls), 6 noobj_ignore_sum
// cnt: int[3][8]  target box region: float4, bases {0, 4056, 20280} (per-image cap g*g*3)

__device__ __forceinline__ float bce(float z, float x) {
    // max(x,0) - x*z + log1p(exp(-|x|))
    return fmaxf(x, 0.f) - x * z + log1pf(expf(-fabsf(x)));
}

__device__ __forceinline__ void decode_blk(int blk, int& layer, int& blk0) {
    if (blk < 16)      { layer = 0; blk0 = 0; }
    else if (blk < 80) { layer = 1; blk0 = 16; }
    else               { layer = 2; blk0 = 80; }
}

__global__ __launch_bounds__(BDIM) void pass_a(
    const float* __restrict__ o0, const float* __restrict__ l0,
    const float* __restrict__ o1, const float* __restrict__ l1,
    const float* __restrict__ o2, const float* __restrict__ l2,
    double* __restrict__ acc, int* __restrict__ cnt, float4* __restrict__ tbox)
{
    int layer, blk0;
    decode_blk(blockIdx.x, layer, blk0);
    const int g     = (layer == 0) ? 13 : (layer == 1) ? 26 : 52;
    const int C     = 8 * g * g * 3;
    const int Nl    = g * g * 3;
    const int tbase = (layer == 0) ? 0 : (layer == 1) ? 4056 : 20280;
    const float* O  = (layer == 0) ? o0 : (layer == 1) ? o1 : o2;
    const float* L  = (layer == 0) ? l0 : (layer == 1) ? l1 : l2;

    int cell = (blockIdx.x - blk0) * BDIM + (int)threadIdx.x;
    float s_xy = 0.f, s_wh = 0.f, s_conf = 0.f, s_cls = 0.f, s_obj = 0.f, s_s1 = 0.f;
    if (cell < C) {
        int a  = cell % 3;
        int xi = (cell / 3) % g;
        int yi = (cell / (3 * g)) % g;
        int b  = cell / (3 * g * g);
        const float* op = O + (size_t)cell * 85;
        const float* lp = L + (size_t)cell * 85;
        float tx = op[0], ty = op[1], tw = op[2], th = op[3], tc = op[4];
        float lx = lp[0], ly = lp[1], lw = lp[2], lh = lp[3], lobj = lp[4];
        float gf = (float)g;
        // raw_true_xy = lab_xy * grid_wh - grid (unmasked, feeds global BCE mean)
        float rtx = lx * gf - (float)xi;
        float rty = ly * gf - (float)yi;
        s_xy = bce(rtx, tx) + bce(rty, ty);
        bool objb = (lobj != 0.f);
        float aw = c_aw[layer][a], ah = c_ah[layer][a];
        float inp = gf * 32.f;
        float rtw = objb ? logf(lw * inp / aw) : 0.f;
        float rth = objb ? logf(lh * inp / ah) : 0.f;
        float bls = 2.f - lw * lh;
        float dw = rtw - tw, dh = rth - th;
        s_wh   = lobj * bls * 0.5f * (dw * dw + dh * dh);
        s_conf = bce(lobj, tc);
        s_obj  = lobj;
        s_s1   = lobj * bls;
        float cl = 0.f;
        #pragma unroll 8
        for (int k = 0; k < 80; k++) cl += bce(lp[5 + k], op[5 + k]);
        s_cls = cl;
        if (objb) {
            int idx = atomicAdd(&cnt[layer * 8 + b], 1);
            tbox[tbase + b * Nl + idx] = make_float4(lx, ly, lw, lh);
        }
    }
    // block reduction: 64-lane shuffle, then 4 wave sums per quantity in LDS
    __shared__ float sb[6][4];
    float v[6] = {s_xy, s_wh, s_conf, s_cls, s_obj, s_s1};
    #pragma unroll
    for (int q = 0; q < 6; q++) {
        float x = v[q];
        #pragma unroll
        for (int off = 32; off > 0; off >>= 1) x += __shfl_down(x, off, 64);
        if ((threadIdx.x & 63) == 0) sb[q][threadIdx.x >> 6] = x;
    }
    __syncthreads();
    if (threadIdx.x < 6) {
        int q = threadIdx.x;
        double s = (double)sb[q][0] + (double)sb[q][1] + (double)sb[q][2] + (double)sb[q][3];
        atomicAdd(&acc[layer * 7 + q], s);
    }
}

__global__ __launch_bounds__(BDIM) void pass_b(
    const float* __restrict__ o0, const float* __restrict__ l0,
    const float* __restrict__ o1, const float* __restrict__ l1,
    const float* __restrict__ o2, const float* __restrict__ l2,
    double* __restrict__ acc, const int* __restrict__ cnt, const float4* __restrict__ tbox)
{
    int layer, blk0;
    decode_blk(blockIdx.x, layer, blk0);
    const int g     = (layer == 0) ? 13 : (layer == 1) ? 26 : 52;
    const int C     = 8 * g * g * 3;
    const int Nl    = g * g * 3;
    const int tbase = (layer == 0) ? 0 : (layer == 1) ? 4056 : 20280;
    const float* O  = (layer == 0) ? o0 : (layer == 1) ? o1 : o2;
    const float* L  = (layer == 0) ? l0 : (layer == 1) ? l1 : l2;

    int cell = (blockIdx.x - blk0) * BDIM + (int)threadIdx.x;
    float v = 0.f;
    if (cell < C) {
        int a  = cell % 3;
        int xi = (cell / 3) % g;
        int yi = (cell / (3 * g)) % g;
        int b  = cell / (3 * g * g);
        const float* op = O + (size_t)cell * 85;
        float tx = op[0], ty = op[1], tw = op[2], th = op[3];
        float lobj = L[(size_t)cell * 85 + 4];
        float gf = (float)g, inp = gf * 32.f;
        float aw = c_aw[layer][a], ah = c_ah[layer][a];
        float px = (1.f / (1.f + expf(-tx)) + (float)xi) / gf;
        float py = (1.f / (1.f + expf(-ty)) + (float)yi) / gf;
        float pw = expf(tw) * aw / inp;
        float ph = expf(th) * ah / inp;
        float pminx = px - pw * 0.5f, pmaxx = px + pw * 0.5f;
        float pminy = py - ph * 0.5f, pmaxy = py + ph * 0.5f;
        float a1 = pw * ph;
        int n = cnt[layer * 8 + b];
        const float4* tp = tbox + tbase + b * Nl;
        float best = -1.f;  // replicates where(valid, iou, -1) floor
        for (int j = 0; j < n; j++) {
            float4 t = tp[j];
            float hw = t.z * 0.5f, hh = t.w * 0.5f;
            // NOTE: reference uses maximum for BOTH mins and maxes (replicated bug)
            float imnx = fmaxf(pminx, t.x - hw);
            float imxx = fmaxf(pmaxx, t.x + hw);
            float imny = fmaxf(pminy, t.y - hh);
            float imxy = fmaxf(pmaxy, t.y + hh);
            float iw = fmaxf(imxx - imnx, 0.f);
            float ih = fmaxf(imxy - imny, 0.f);
            float inter = iw * ih;
            float iou = inter / (a1 + t.z * t.w - inter);
            best = fmaxf(best, iou);
        }
        v = (best < 0.5f) ? (1.f - lobj) : 0.f;  // (1-obj)*ignore
    }
    __shared__ float sb[4];
    float x = v;
    #pragma unroll
    for (int off = 32; off > 0; off >>= 1) x += __shfl_down(x, off, 64);
    if ((threadIdx.x & 63) == 0) sb[threadIdx.x >> 6] = x;
    __syncthreads();
    if (threadIdx.x == 0) {
        double s = (double)sb[0] + (double)sb[1] + (double)sb[2] + (double)sb[3];
        atomicAdd(&acc[layer * 7 + 6], s);
    }
}

__global__ void finalize_k(const double* __restrict__ acc, float* __restrict__ out)
{
    if (threadIdx.x == 0 && blockIdx.x == 0) {
        double loss = 0.0;
        const int gs[3] = {13, 26, 52};
        for (int l = 0; l < 3; l++) {
            double C   = 8.0 * gs[l] * gs[l] * 3.0;
            double bxy = acc[l * 7 + 0] / (C * 2.0);   // mean over (...,2)
            double wh  = acc[l * 7 + 1];               // elementwise sum
            double cf  = acc[l * 7 + 2] / C;           // mean over (...,1)
            double cm  = acc[l * 7 + 3] / (C * 80.0);  // mean over (...,80)
            double ob  = acc[l * 7 + 4];
            double s1  = acc[l * 7 + 5];
            double ni  = acc[l * 7 + 6];
            loss += (bxy * s1 + wh + cf * (ob + ni) + cm * ob) / 8.0;
        }
        out[0] = (float)loss;
    }
}

extern "C" void kernel_launch(void* const* d_in, const int* in_sizes, int n_in,
                              void* d_out, int out_size, void* d_ws, size_t ws_size,
                              hipStream_t stream)
{
    // setup_inputs dict order: o0, l0, o1, l1, o2, l2
    const float* o0 = (const float*)d_in[0];
    const float* l0 = (const float*)d_in[1];
    const float* o1 = (const float*)d_in[2];
    const float* l1 = (const float*)d_in[3];
    const float* o2 = (const float*)d_in[4];
    const float* l2 = (const float*)d_in[5];

    double* acc  = (double*)d_ws;                        // 21 doubles @ 0
    int*    cnt  = (int*)((char*)d_ws + 192);            // 24 ints
    float4* tbox = (float4*)((char*)d_ws + 512);         // 85176 float4 = ~1.33 MB

    hipMemsetAsync(d_ws, 0, 512, stream);                // zero acc + cnt (ws is poisoned)
    pass_a<<<334, BDIM, 0, stream>>>(o0, l0, o1, l1, o2, l2, acc, cnt, tbox);
    pass_b<<<334, BDIM, 0, stream>>>(o0, l0, o1, l1, o2, l2, acc, cnt, tbox);
    finalize_k<<<1, 64, 0, stream>>>(acc, (float*)d_out);
}